// Round 2
// baseline (10528.863 us; speedup 1.0000x reference)
//
#include <hip/hip_runtime.h>
#include <hip/hip_bf16.h>

// Problem constants (from reference): b=2, s=2048, d_in=2048, nh=16, kv=4, hd=128
#define B  2
#define S  2048
#define D  2048
#define NH 16
#define KV 4
#define HD 128
#define G  (NH / KV)   // 4
#define M_ROWS (B * S) // 4096

// ---------------------------------------------------------------------------
// Tiled GEMM: X (M x D, fp32, row-major) @ W (D x N, fp32, row-major)
// -> out in head-major fp32 layout: out[((b*H + h)*S + si)*HD + d]
//    where m = b*S + si, n = h*HD + d.
// Tile 64x64, BK=16, 256 threads (16x16), 4x4 per thread.
// ---------------------------------------------------------------------------
__global__ __launch_bounds__(256) void proj_gemm(const float* __restrict__ X,
                                                 const float* __restrict__ W,
                                                 float* __restrict__ out,
                                                 int N, int H) {
    const int m0 = blockIdx.y * 64;
    const int n0 = blockIdx.x * 64;
    __shared__ float As[16][65]; // [k][m]
    __shared__ float Bs[16][65]; // [k][n]
    const int tx = threadIdx.x, ty = threadIdx.y;
    const int tid = ty * 16 + tx;

    float acc[4][4] = {};

    for (int k0 = 0; k0 < D; k0 += 16) {
#pragma unroll
        for (int i = 0; i < 4; i++) {
            int lin = tid + i * 256;      // 0..1023 over 64x16 A tile
            int row = lin >> 4;
            int col = lin & 15;
            As[col][row] = X[(size_t)(m0 + row) * D + k0 + col];
        }
#pragma unroll
        for (int i = 0; i < 4; i++) {
            int lin = tid + i * 256;      // 0..1023 over 16x64 B tile
            int row = lin >> 6;
            int col = lin & 63;
            Bs[row][col] = W[(size_t)(k0 + row) * N + n0 + col];
        }
        __syncthreads();
#pragma unroll
        for (int kk = 0; kk < 16; kk++) {
            float a[4], bb[4];
#pragma unroll
            for (int i = 0; i < 4; i++) a[i] = As[kk][ty * 4 + i];
#pragma unroll
            for (int j = 0; j < 4; j++) bb[j] = Bs[kk][tx * 4 + j];
#pragma unroll
            for (int i = 0; i < 4; i++)
#pragma unroll
                for (int j = 0; j < 4; j++) acc[i][j] += a[i] * bb[j];
        }
        __syncthreads();
    }

#pragma unroll
    for (int i = 0; i < 4; i++) {
        int m = m0 + ty * 4 + i;
        int bb_ = m >> 11;      // / S
        int si  = m & (S - 1);
#pragma unroll
        for (int j = 0; j < 4; j++) {
            int n = n0 + tx * 4 + j;
            int h = n >> 7;     // / HD
            int d = n & (HD - 1);
            out[(((size_t)(bb_ * H + h)) * S + si) * HD + d] = acc[i][j];
        }
    }
}

// ---------------------------------------------------------------------------
// Output GEMM: Ctx (M x D fp32, row-major) @ Wo (D x D fp32) -> fp32 out
// ---------------------------------------------------------------------------
__global__ __launch_bounds__(256) void out_gemm(const float* __restrict__ A,
                                                const float* __restrict__ W,
                                                float* __restrict__ out) {
    const int m0 = blockIdx.y * 64;
    const int n0 = blockIdx.x * 64;
    __shared__ float As[16][65];
    __shared__ float Bs[16][65];
    const int tx = threadIdx.x, ty = threadIdx.y;
    const int tid = ty * 16 + tx;

    float acc[4][4] = {};

    for (int k0 = 0; k0 < D; k0 += 16) {
#pragma unroll
        for (int i = 0; i < 4; i++) {
            int lin = tid + i * 256;
            int row = lin >> 4;
            int col = lin & 15;
            As[col][row] = A[(size_t)(m0 + row) * D + k0 + col];
        }
#pragma unroll
        for (int i = 0; i < 4; i++) {
            int lin = tid + i * 256;
            int row = lin >> 6;
            int col = lin & 63;
            Bs[row][col] = W[(size_t)(k0 + row) * D + n0 + col];
        }
        __syncthreads();
#pragma unroll
        for (int kk = 0; kk < 16; kk++) {
            float a[4], bb[4];
#pragma unroll
            for (int i = 0; i < 4; i++) a[i] = As[kk][ty * 4 + i];
#pragma unroll
            for (int j = 0; j < 4; j++) bb[j] = Bs[kk][tx * 4 + j];
#pragma unroll
            for (int i = 0; i < 4; i++)
#pragma unroll
                for (int j = 0; j < 4; j++) acc[i][j] += a[i] * bb[j];
        }
        __syncthreads();
    }

#pragma unroll
    for (int i = 0; i < 4; i++) {
        int m = m0 + ty * 4 + i;
#pragma unroll
        for (int j = 0; j < 4; j++) {
            int n = n0 + tx * 4 + j;
            out[(size_t)m * D + n] = acc[i][j];
        }
    }
}

// ---------------------------------------------------------------------------
// RMSNorm (over hd=128) + RoPE, in place on fp32 head-major data.
// One 128-thread block per (b, h, s) row.  Layout: row r = (b*H + h)*S + si.
// ---------------------------------------------------------------------------
__global__ __launch_bounds__(128) void rms_rope(float* __restrict__ data,
                                                const float* __restrict__ scale,
                                                const float* __restrict__ cosT,
                                                const float* __restrict__ sinT) {
    const int r = blockIdx.x;
    const int d = threadIdx.x;
    const int si = r & (S - 1);
    float* row = data + (size_t)r * HD;

    float val = row[d];

    __shared__ float red[HD];
    __shared__ float nrm[HD];
    red[d] = val * val;
    __syncthreads();
#pragma unroll
    for (int off = 64; off > 0; off >>= 1) {
        if (d < off) red[d] += red[d + off];
        __syncthreads();
    }
    const float ms = red[0] * (1.0f / HD);
    const float rinv = rsqrtf(ms + 1e-6f);

    const float nv = val * rinv * scale[d];
    nrm[d] = nv;
    __syncthreads();

    const int pd = (d < 64) ? (d + 64) : (d - 64);
    const float part = nrm[pd];
    const float rot = (d < 64) ? -part : part;

    const float c = cosT[(size_t)si * HD + d];
    const float s = sinT[(size_t)si * HD + d];

    row[d] = nv * c + rot * s;
}

// ---------------------------------------------------------------------------
// Causal GQA attention, one 128-thread block per (b, head, q_row).
// q: (b, NH, S, HD) fp32; k,v: (b, KV, S, HD) fp32.
// ctx out: laid out as (b, s, nh, hd) => row-major (M_ROWS, NH*HD).
// ---------------------------------------------------------------------------
__global__ __launch_bounds__(128) void attn(const float* __restrict__ q,
                                            const float* __restrict__ k,
                                            const float* __restrict__ v,
                                            float* __restrict__ ctx) {
    const int qi = blockIdx.x;
    const int h  = blockIdx.y;
    const int b  = blockIdx.z;
    const int kvh = h / G;
    const int tid = threadIdx.x;

    const float* qrow  = q + (((size_t)(b * NH + h)) * S + qi) * HD;
    const float* kbase = k + ((size_t)(b * KV + kvh)) * S * HD;
    const float* vbase = v + ((size_t)(b * KV + kvh)) * S * HD;

    __shared__ float qs[HD];
    __shared__ float sc[S];
    __shared__ float red[128];

    qs[tid] = qrow[tid];
    __syncthreads();

    const int n = qi + 1;
    const float inv_sqrt_hd = 0.08838834764831845f; // 1/sqrt(128)

    // scores
    for (int t = tid; t < n; t += 128) {
        const float* kr = kbase + (size_t)t * HD;
        float dot = 0.0f;
#pragma unroll 4
        for (int d = 0; d < HD; d++) dot += qs[d] * kr[d];
        sc[t] = dot * inv_sqrt_hd;
    }
    __syncthreads();

    // max
    float lm = -1e30f;
    for (int t = tid; t < n; t += 128) lm = fmaxf(lm, sc[t]);
    red[tid] = lm;
    __syncthreads();
#pragma unroll
    for (int off = 64; off > 0; off >>= 1) {
        if (tid < off) red[tid] = fmaxf(red[tid], red[tid + off]);
        __syncthreads();
    }
    const float mval = red[0];
    __syncthreads();

    // exp + sum
    float ls = 0.0f;
    for (int t = tid; t < n; t += 128) {
        float e = __expf(sc[t] - mval);
        sc[t] = e;
        ls += e;
    }
    red[tid] = ls;
    __syncthreads();
#pragma unroll
    for (int off = 64; off > 0; off >>= 1) {
        if (tid < off) red[tid] += red[tid + off];
        __syncthreads();
    }
    const float linv = 1.0f / red[0];
    __syncthreads();

    // ctx[d] = sum_t w_t * v[t][d]
    float acc = 0.0f;
    for (int t = 0; t < n; t++) {
        acc += sc[t] * vbase[(size_t)t * HD + tid];
    }
    ctx[(((size_t)(b * S + qi)) * NH + h) * HD + tid] = acc * linv;
}

// ---------------------------------------------------------------------------
extern "C" void kernel_launch(void* const* d_in, const int* in_sizes, int n_in,
                              void* d_out, int out_size, void* d_ws, size_t ws_size,
                              hipStream_t stream) {
    const float* x    = (const float*)d_in[0];
    // d_in[1] = mask (bool) — causality is handled arithmetically, unused.
    const float* cosT = (const float*)d_in[2];
    const float* sinT = (const float*)d_in[3];
    const float* Wq   = (const float*)d_in[4];
    const float* Wk   = (const float*)d_in[5];
    const float* Wv   = (const float*)d_in[6];
    const float* Wo   = (const float*)d_in[7];
    const float* qsc  = (const float*)d_in[8];
    const float* ksc  = (const float*)d_in[9];
    float* out = (float*)d_out;

    float* q_ws = (float*)d_ws;                            // B*NH*S*HD = 8388608
    float* k_ws = q_ws + (size_t)B * NH * S * HD;          // B*KV*S*HD = 2097152
    float* v_ws = k_ws + (size_t)B * KV * S * HD;
    float* c_ws = v_ws + (size_t)B * KV * S * HD;          // B*S*NH*HD = 8388608

    dim3 blk(16, 16);

    // Projections
    proj_gemm<<<dim3((NH * HD) / 64, M_ROWS / 64), blk, 0, stream>>>(x, Wq, q_ws, NH * HD, NH);
    proj_gemm<<<dim3((KV * HD) / 64, M_ROWS / 64), blk, 0, stream>>>(x, Wk, k_ws, KV * HD, KV);
    proj_gemm<<<dim3((KV * HD) / 64, M_ROWS / 64), blk, 0, stream>>>(x, Wv, v_ws, KV * HD, KV);

    // RMSNorm + RoPE on q and k
    rms_rope<<<B * NH * S, 128, 0, stream>>>(q_ws, qsc, cosT, sinT);
    rms_rope<<<B * KV * S, 128, 0, stream>>>(k_ws, ksc, cosT, sinT);

    // Attention
    attn<<<dim3(S, NH, B), 128, 0, stream>>>(q_ws, k_ws, v_ws, c_ws);

    // Output projection
    out_gemm<<<dim3(D / 64, M_ROWS / 64), blk, 0, stream>>>(c_ws, Wo, out);
}

// Round 3
// 3044.856 us; speedup vs baseline: 3.4579x; 3.4579x over previous
//
#include <hip/hip_runtime.h>
#include <hip/hip_bf16.h>
#include <math.h>

// Problem constants (from reference): b=2, s=2048, d_in=2048, nh=16, kv=4, hd=128
#define B  2
#define S  2048
#define D  2048
#define NH 16
#define KV 4
#define HD 128
#define G  (NH / KV)   // 4
#define M_ROWS (B * S) // 4096

// ---------------------------------------------------------------------------
// Tiled GEMM: X (M x D, fp32, row-major) @ W (D x N, fp32, row-major)
// -> out in head-major fp32 layout: out[((b*H + h)*S + si)*HD + d]
// Tile 64x64, BK=16, 256 threads (16x16), 4x4 per thread.
// ---------------------------------------------------------------------------
__global__ __launch_bounds__(256) void proj_gemm(const float* __restrict__ X,
                                                 const float* __restrict__ W,
                                                 float* __restrict__ out,
                                                 int N, int H) {
    const int m0 = blockIdx.y * 64;
    const int n0 = blockIdx.x * 64;
    __shared__ float As[16][65]; // [k][m]
    __shared__ float Bs[16][65]; // [k][n]
    const int tx = threadIdx.x, ty = threadIdx.y;
    const int tid = ty * 16 + tx;

    float acc[4][4] = {};

    for (int k0 = 0; k0 < D; k0 += 16) {
#pragma unroll
        for (int i = 0; i < 4; i++) {
            int lin = tid + i * 256;      // 0..1023 over 64x16 A tile
            int row = lin >> 4;
            int col = lin & 15;
            As[col][row] = X[(size_t)(m0 + row) * D + k0 + col];
        }
#pragma unroll
        for (int i = 0; i < 4; i++) {
            int lin = tid + i * 256;      // 0..1023 over 16x64 B tile
            int row = lin >> 6;
            int col = lin & 63;
            Bs[row][col] = W[(size_t)(k0 + row) * N + n0 + col];
        }
        __syncthreads();
#pragma unroll
        for (int kk = 0; kk < 16; kk++) {
            float a[4], bb[4];
#pragma unroll
            for (int i = 0; i < 4; i++) a[i] = As[kk][ty * 4 + i];
#pragma unroll
            for (int j = 0; j < 4; j++) bb[j] = Bs[kk][tx * 4 + j];
#pragma unroll
            for (int i = 0; i < 4; i++)
#pragma unroll
                for (int j = 0; j < 4; j++) acc[i][j] += a[i] * bb[j];
        }
        __syncthreads();
    }

#pragma unroll
    for (int i = 0; i < 4; i++) {
        int m = m0 + ty * 4 + i;
        int bb_ = m >> 11;      // / S
        int si  = m & (S - 1);
#pragma unroll
        for (int j = 0; j < 4; j++) {
            int n = n0 + tx * 4 + j;
            int h = n >> 7;     // / HD
            int d = n & (HD - 1);
            out[(((size_t)(bb_ * H + h)) * S + si) * HD + d] = acc[i][j];
        }
    }
}

// ---------------------------------------------------------------------------
// Output GEMM: Ctx (M x D fp32, row-major) @ Wo (D x D fp32) -> fp32 out
// ---------------------------------------------------------------------------
__global__ __launch_bounds__(256) void out_gemm(const float* __restrict__ A,
                                                const float* __restrict__ W,
                                                float* __restrict__ out) {
    const int m0 = blockIdx.y * 64;
    const int n0 = blockIdx.x * 64;
    __shared__ float As[16][65];
    __shared__ float Bs[16][65];
    const int tx = threadIdx.x, ty = threadIdx.y;
    const int tid = ty * 16 + tx;

    float acc[4][4] = {};

    for (int k0 = 0; k0 < D; k0 += 16) {
#pragma unroll
        for (int i = 0; i < 4; i++) {
            int lin = tid + i * 256;
            int row = lin >> 4;
            int col = lin & 15;
            As[col][row] = A[(size_t)(m0 + row) * D + k0 + col];
        }
#pragma unroll
        for (int i = 0; i < 4; i++) {
            int lin = tid + i * 256;
            int row = lin >> 6;
            int col = lin & 63;
            Bs[row][col] = W[(size_t)(k0 + row) * D + n0 + col];
        }
        __syncthreads();
#pragma unroll
        for (int kk = 0; kk < 16; kk++) {
            float a[4], bb[4];
#pragma unroll
            for (int i = 0; i < 4; i++) a[i] = As[kk][ty * 4 + i];
#pragma unroll
            for (int j = 0; j < 4; j++) bb[j] = Bs[kk][tx * 4 + j];
#pragma unroll
            for (int i = 0; i < 4; i++)
#pragma unroll
                for (int j = 0; j < 4; j++) acc[i][j] += a[i] * bb[j];
        }
        __syncthreads();
    }

#pragma unroll
    for (int i = 0; i < 4; i++) {
        int m = m0 + ty * 4 + i;
#pragma unroll
        for (int j = 0; j < 4; j++) {
            int n = n0 + tx * 4 + j;
            out[(size_t)m * D + n] = acc[i][j];
        }
    }
}

// ---------------------------------------------------------------------------
// RMSNorm (over hd=128) + RoPE, in place on fp32 head-major data.
// ---------------------------------------------------------------------------
__global__ __launch_bounds__(128) void rms_rope(float* __restrict__ data,
                                                const float* __restrict__ scale,
                                                const float* __restrict__ cosT,
                                                const float* __restrict__ sinT) {
    const int r = blockIdx.x;
    const int d = threadIdx.x;
    const int si = r & (S - 1);
    float* row = data + (size_t)r * HD;

    float val = row[d];

    __shared__ float red[HD];
    __shared__ float nrm[HD];
    red[d] = val * val;
    __syncthreads();
#pragma unroll
    for (int off = 64; off > 0; off >>= 1) {
        if (d < off) red[d] += red[d + off];
        __syncthreads();
    }
    const float ms = red[0] * (1.0f / HD);
    const float rinv = rsqrtf(ms + 1e-6f);

    const float nv = val * rinv * scale[d];
    nrm[d] = nv;
    __syncthreads();

    const int pd = (d < 64) ? (d + 64) : (d - 64);
    const float part = nrm[pd];
    const float rot = (d < 64) ? -part : part;

    const float c = cosT[(size_t)si * HD + d];
    const float s = sinT[(size_t)si * HD + d];

    row[d] = nv * c + rot * s;
}

// ---------------------------------------------------------------------------
// Flash-style causal GQA attention.
// One 256-thread block (16x16) per (b, h, 64-row Q tile).
// K/V tiles of 32 rows staged in LDS; online softmax; P via LDS round-trip.
// q: (b, NH, S, HD) fp32; k,v: (b, KV, S, HD) fp32.
// ctx out: (b, s, nh, hd) row-major.
// Scores micro-tile: 4 rows (ty*4..+3) x 2 cols (tx*2..+1).
// O accumulator: 4 rows x 8 cols (tx*8..+7).
// Row-group = 16 contiguous lanes (same ty) -> shfl_xor masks 1,2,4,8.
// ---------------------------------------------------------------------------
__global__ __launch_bounds__(256) void flash_attn(const float* __restrict__ q,
                                                  const float* __restrict__ k,
                                                  const float* __restrict__ v,
                                                  float* __restrict__ ctx) {
    const int q0 = blockIdx.x * 64;
    const int h  = blockIdx.y;
    const int b  = blockIdx.z;
    const int kvh = h / G;
    const int tx = threadIdx.x, ty = threadIdx.y;
    const int tid = ty * 16 + tx;

    // pads chosen for conflict-free b128/b64 micro-kernel reads (68*4%16==0)
    __shared__ float Qs[128][68];  // [d][q]  34.8 KB
    __shared__ float Ks[128][36];  // [d][t]  18.4 KB
    __shared__ float Vs[32][128];  // [t][d]  16.4 KB
    __shared__ float Ps[32][68];   // [t][q]   8.7 KB

    const float* qbase = q + ((size_t)(b * NH + h)) * S * HD;
    const float* kbase = k + ((size_t)(b * KV + kvh)) * S * HD;
    const float* vbase = v + ((size_t)(b * KV + kvh)) * S * HD;

    // stage Q tile (transposed): 64 rows x 128 d
#pragma unroll
    for (int p = 0; p < 8; p++) {
        int lin = tid + p * 256;          // 0..2047
        int d4  = (lin & 31) * 4;
        int qq  = lin >> 5;               // 0..63
        const float4 val = *(const float4*)(qbase + (size_t)(q0 + qq) * HD + d4);
        Qs[d4 + 0][qq] = val.x;
        Qs[d4 + 1][qq] = val.y;
        Qs[d4 + 2][qq] = val.z;
        Qs[d4 + 3][qq] = val.w;
    }

    float o[4][8] = {};
    float m_i[4], l_i[4];
#pragma unroll
    for (int i = 0; i < 4; i++) { m_i[i] = -INFINITY; l_i[i] = 0.0f; }

    const float scale = 0.08838834764831845f; // 1/sqrt(128)

    for (int t0 = 0; t0 < q0 + 64; t0 += 32) {
        __syncthreads(); // previous iteration done with Ks/Vs/Ps (also covers Qs staging, 1st iter)

        // stage K (transposed) and V (natural): 32 rows x 128 d each
#pragma unroll
        for (int p = 0; p < 4; p++) {
            int lin = tid + p * 256;      // 0..1023
            int d4  = (lin & 31) * 4;
            int tt  = lin >> 5;           // 0..31
            const float4 kv4 = *(const float4*)(kbase + (size_t)(t0 + tt) * HD + d4);
            Ks[d4 + 0][tt] = kv4.x;
            Ks[d4 + 1][tt] = kv4.y;
            Ks[d4 + 2][tt] = kv4.z;
            Ks[d4 + 3][tt] = kv4.w;
            *(float4*)&Vs[tt][d4] = *(const float4*)(vbase + (size_t)(t0 + tt) * HD + d4);
        }
        __syncthreads();

        // ---- scores: Sc[64q][32t] = Q . K^T, K-dim 128 ----
        float s[4][2] = {};
#pragma unroll 8
        for (int kk = 0; kk < 128; kk++) {
            float a[4], bb[2];
#pragma unroll
            for (int i = 0; i < 4; i++) a[i] = Qs[kk][ty * 4 + i];
#pragma unroll
            for (int j = 0; j < 2; j++) bb[j] = Ks[kk][tx * 2 + j];
#pragma unroll
            for (int i = 0; i < 4; i++)
#pragma unroll
                for (int j = 0; j < 2; j++) s[i][j] += a[i] * bb[j];
        }

        // ---- online softmax (per row) ----
#pragma unroll
        for (int i = 0; i < 4; i++) {
            const int qg = q0 + ty * 4 + i;
#pragma unroll
            for (int j = 0; j < 2; j++) {
                const int tg = t0 + tx * 2 + j;
                s[i][j] = (tg > qg) ? -INFINITY : s[i][j] * scale;
            }
            float tmax = fmaxf(s[i][0], s[i][1]);
#pragma unroll
            for (int msk = 1; msk < 16; msk <<= 1)
                tmax = fmaxf(tmax, __shfl_xor(tmax, msk, 64));

            const float mnew  = fmaxf(m_i[i], tmax);
            const float alpha = __expf(m_i[i] - mnew); // first tile: exp(-inf)=0
            const float p0 = __expf(s[i][0] - mnew);
            const float p1 = __expf(s[i][1] - mnew);
            float psum = p0 + p1;
#pragma unroll
            for (int msk = 1; msk < 16; msk <<= 1)
                psum += __shfl_xor(psum, msk, 64);

            l_i[i] = l_i[i] * alpha + psum;
            m_i[i] = mnew;
#pragma unroll
            for (int c = 0; c < 8; c++) o[i][c] *= alpha;

            Ps[tx * 2 + 0][ty * 4 + i] = p0;
            Ps[tx * 2 + 1][ty * 4 + i] = p1;
        }
        __syncthreads();

        // ---- PV: O[64q][128d] += P(64x32) . V(32x128) ----
#pragma unroll 4
        for (int kk = 0; kk < 32; kk++) {
            float a[4], bb[8];
#pragma unroll
            for (int i = 0; i < 4; i++) a[i] = Ps[kk][ty * 4 + i];
#pragma unroll
            for (int c = 0; c < 8; c++) bb[c] = Vs[kk][tx * 8 + c];
#pragma unroll
            for (int i = 0; i < 4; i++)
#pragma unroll
                for (int c = 0; c < 8; c++) o[i][c] += a[i] * bb[c];
        }
    }

    // ---- epilogue: normalize and store ----
#pragma unroll
    for (int i = 0; i < 4; i++) {
        const float inv = 1.0f / l_i[i];
        const int qg = q0 + ty * 4 + i;
        float* dst = ctx + (((size_t)(b * S + qg)) * NH + h) * HD + tx * 8;
#pragma unroll
        for (int c = 0; c < 8; c++) dst[c] = o[i][c] * inv;
    }
}

// ---------------------------------------------------------------------------
extern "C" void kernel_launch(void* const* d_in, const int* in_sizes, int n_in,
                              void* d_out, int out_size, void* d_ws, size_t ws_size,
                              hipStream_t stream) {
    const float* x    = (const float*)d_in[0];
    // d_in[1] = mask (bool) — causality is handled arithmetically, unused.
    const float* cosT = (const float*)d_in[2];
    const float* sinT = (const float*)d_in[3];
    const float* Wq   = (const float*)d_in[4];
    const float* Wk   = (const float*)d_in[5];
    const float* Wv   = (const float*)d_in[6];
    const float* Wo   = (const float*)d_in[7];
    const float* qsc  = (const float*)d_in[8];
    const float* ksc  = (const float*)d_in[9];
    float* out = (float*)d_out;

    float* q_ws = (float*)d_ws;                            // B*NH*S*HD = 8388608
    float* k_ws = q_ws + (size_t)B * NH * S * HD;          // B*KV*S*HD = 2097152
    float* v_ws = k_ws + (size_t)B * KV * S * HD;
    float* c_ws = v_ws + (size_t)B * KV * S * HD;          // B*S*NH*HD = 8388608

    dim3 blk(16, 16);

    // Projections
    proj_gemm<<<dim3((NH * HD) / 64, M_ROWS / 64), blk, 0, stream>>>(x, Wq, q_ws, NH * HD, NH);
    proj_gemm<<<dim3((KV * HD) / 64, M_ROWS / 64), blk, 0, stream>>>(x, Wk, k_ws, KV * HD, KV);
    proj_gemm<<<dim3((KV * HD) / 64, M_ROWS / 64), blk, 0, stream>>>(x, Wv, v_ws, KV * HD, KV);

    // RMSNorm + RoPE on q and k
    rms_rope<<<B * NH * S, 128, 0, stream>>>(q_ws, qsc, cosT, sinT);
    rms_rope<<<B * KV * S, 128, 0, stream>>>(k_ws, ksc, cosT, sinT);

    // Flash attention
    flash_attn<<<dim3(S / 64, NH, B), blk, 0, stream>>>(q_ws, k_ws, v_ws, c_ws);

    // Output projection
    out_gemm<<<dim3(D / 64, M_ROWS / 64), blk, 0, stream>>>(c_ws, Wo, out);
}

// Round 4
// 1622.384 us; speedup vs baseline: 6.4897x; 1.8768x over previous
//
#include <hip/hip_runtime.h>
#include <hip/hip_bf16.h>
#include <math.h>

// Problem constants: b=2, s=2048, d_in=2048, nh=16, kv=4, hd=128
#define B  2
#define S  2048
#define D  2048
#define NH 16
#define KV 4
#define HD 128
#define G  (NH / KV)   // 4
#define M_ROWS (B * S) // 4096

typedef __hip_bfloat16 bf16;
typedef __attribute__((ext_vector_type(8))) short s16x8;   // 8 bf16 (4 VGPRs)
typedef __attribute__((ext_vector_type(4))) float f32x4;   // MFMA acc

// ---------------------------------------------------------------------------
// fp32 -> bf16 cast (4 elems/thread)
// ---------------------------------------------------------------------------
__global__ __launch_bounds__(256) void cast_f32_bf16(const float* __restrict__ in,
                                                     bf16* __restrict__ o, int n4) {
    int i = blockIdx.x * 256 + threadIdx.x;
    if (i >= n4) return;
    float4 v = ((const float4*)in)[i];
    bf16 a0 = __float2bfloat16(v.x), a1 = __float2bfloat16(v.y);
    bf16 a2 = __float2bfloat16(v.z), a3 = __float2bfloat16(v.w);
    ushort4 u;
    u.x = *(unsigned short*)&a0; u.y = *(unsigned short*)&a1;
    u.z = *(unsigned short*)&a2; u.w = *(unsigned short*)&a3;
    ((ushort4*)o)[i] = u;
}

// ---------------------------------------------------------------------------
// W (K x N fp32, row-major) -> Wt (N x K bf16, row-major), tiled transpose
// grid: (N/32, K/32), 256 threads
// ---------------------------------------------------------------------------
__global__ __launch_bounds__(256) void tcast(const float* __restrict__ W,
                                             bf16* __restrict__ Wt, int K, int N) {
    __shared__ float T[32][33];
    const int n0 = blockIdx.x * 32, k0 = blockIdx.y * 32;
    const int tx = threadIdx.x & 31, ty = threadIdx.x >> 5; // ty 0..7
#pragma unroll
    for (int i = 0; i < 4; i++)
        T[ty + i * 8][tx] = W[(size_t)(k0 + ty + i * 8) * N + n0 + tx];
    __syncthreads();
#pragma unroll
    for (int i = 0; i < 4; i++)
        Wt[(size_t)(n0 + ty + i * 8) * K + k0 + tx] = __float2bfloat16(T[tx][ty + i * 8]);
}

// ---------------------------------------------------------------------------
// MFMA GEMM: A (M x K bf16, row-major) @ Bt (N x K bf16, row-major) -> fp32.
// Block tile 128x128, BK=32, 256 threads = 4 waves (64x64 quadrant each,
// 4x4 grid of 16x16x32 MFMA tiles). LDS rows padded to 40 elems (80 B).
// PROJ: out[((b*H + h)*S + si)*HD + d]; else plain out[m*N + n].
// ---------------------------------------------------------------------------
template<bool PROJ>
__global__ __launch_bounds__(256) void gemm_bt(const bf16* __restrict__ A,
                                               const bf16* __restrict__ Bt,
                                               float* __restrict__ out,
                                               int N, int K, int H) {
    const int m0 = blockIdx.y * 128;
    const int n0 = blockIdx.x * 128;
    const int tid  = threadIdx.x;
    const int wave = tid >> 6;
    const int lane = tid & 63;
    const int mw = (wave >> 1) * 64;
    const int nw = (wave & 1) * 64;

    __shared__ short Al[128 * 40];
    __shared__ short Bl[128 * 40];

    f32x4 acc[4][4] = {};

    const int fr = lane & 15;           // fragment row (m or n)
    const int fq = (lane >> 4) * 8;     // k sub-offset

    for (int k0 = 0; k0 < K; k0 += 32) {
        __syncthreads();
        // stage A and Bt tiles: 128 rows x 32 k each; 2 chunks/thread
#pragma unroll
        for (int cc = 0; cc < 2; cc++) {
            int c = tid + cc * 256;
            int row = c >> 2, part = (c & 3) * 8;
            *(uint4*)(&Al[row * 40 + part]) =
                *(const uint4*)(A + (size_t)(m0 + row) * K + k0 + part);
            *(uint4*)(&Bl[row * 40 + part]) =
                *(const uint4*)(Bt + (size_t)(n0 + row) * K + k0 + part);
        }
        __syncthreads();

        s16x8 af[4], bfr[4];
#pragma unroll
        for (int i = 0; i < 4; i++) {
            af[i]  = *(const s16x8*)(&Al[(mw + i * 16 + fr) * 40 + fq]);
            bfr[i] = *(const s16x8*)(&Bl[(nw + i * 16 + fr) * 40 + fq]);
        }
#pragma unroll
        for (int i = 0; i < 4; i++)
#pragma unroll
            for (int j = 0; j < 4; j++)
                acc[i][j] = __builtin_amdgcn_mfma_f32_16x16x32_bf16(af[i], bfr[j], acc[i][j], 0, 0, 0);
    }

    // epilogue: C/D layout col=lane&15, row=(lane>>4)*4+reg
    const int col_l = lane & 15;
    const int row_l = (lane >> 4) * 4;
#pragma unroll
    for (int i = 0; i < 4; i++)
#pragma unroll
        for (int j = 0; j < 4; j++)
#pragma unroll
            for (int r = 0; r < 4; r++) {
                int m = m0 + mw + i * 16 + row_l + r;
                int n = n0 + nw + j * 16 + col_l;
                if (PROJ) {
                    int bb = m >> 11, si = m & (S - 1);
                    int h = n >> 7, d = n & (HD - 1);
                    out[(((size_t)(bb * H + h)) * S + si) * HD + d] = acc[i][j][r];
                } else {
                    out[(size_t)m * N + n] = acc[i][j][r];
                }
            }
}

// ---------------------------------------------------------------------------
// RMSNorm (over hd=128) + RoPE, in place on fp32 head-major data.
// ---------------------------------------------------------------------------
__global__ __launch_bounds__(128) void rms_rope(float* __restrict__ data,
                                                const float* __restrict__ scale,
                                                const float* __restrict__ cosT,
                                                const float* __restrict__ sinT) {
    const int r = blockIdx.x;
    const int d = threadIdx.x;
    const int si = r & (S - 1);
    float* row = data + (size_t)r * HD;

    float val = row[d];

    __shared__ float red[HD];
    __shared__ float nrm[HD];
    red[d] = val * val;
    __syncthreads();
#pragma unroll
    for (int off = 64; off > 0; off >>= 1) {
        if (d < off) red[d] += red[d + off];
        __syncthreads();
    }
    const float ms = red[0] * (1.0f / HD);
    const float rinv = rsqrtf(ms + 1e-6f);

    const float nv = val * rinv * scale[d];
    nrm[d] = nv;
    __syncthreads();

    const int pd = (d < 64) ? (d + 64) : (d - 64);
    const float part = nrm[pd];
    const float rot = (d < 64) ? -part : part;

    const float c = cosT[(size_t)si * HD + d];
    const float s = sinT[(size_t)si * HD + d];

    row[d] = nv * c + rot * s;
}

// ---------------------------------------------------------------------------
// Flash-style causal GQA attention (fp32 in, bf16 ctx out).
// One 256-thread block (16x16) per (b, h, 64-row Q tile).
// ---------------------------------------------------------------------------
__global__ __launch_bounds__(256) void flash_attn(const float* __restrict__ q,
                                                  const float* __restrict__ k,
                                                  const float* __restrict__ v,
                                                  bf16* __restrict__ ctx) {
    const int q0 = blockIdx.x * 64;
    const int h  = blockIdx.y;
    const int b  = blockIdx.z;
    const int kvh = h / G;
    const int tx = threadIdx.x, ty = threadIdx.y;
    const int tid = ty * 16 + tx;

    __shared__ float Qs[128][68];
    __shared__ float Ks[128][36];
    __shared__ float Vs[32][128];
    __shared__ float Ps[32][68];

    const float* qbase = q + ((size_t)(b * NH + h)) * S * HD;
    const float* kbase = k + ((size_t)(b * KV + kvh)) * S * HD;
    const float* vbase = v + ((size_t)(b * KV + kvh)) * S * HD;

#pragma unroll
    for (int p = 0; p < 8; p++) {
        int lin = tid + p * 256;
        int d4  = (lin & 31) * 4;
        int qq  = lin >> 5;
        const float4 val = *(const float4*)(qbase + (size_t)(q0 + qq) * HD + d4);
        Qs[d4 + 0][qq] = val.x;
        Qs[d4 + 1][qq] = val.y;
        Qs[d4 + 2][qq] = val.z;
        Qs[d4 + 3][qq] = val.w;
    }

    float o[4][8] = {};
    float m_i[4], l_i[4];
#pragma unroll
    for (int i = 0; i < 4; i++) { m_i[i] = -INFINITY; l_i[i] = 0.0f; }

    const float scale = 0.08838834764831845f; // 1/sqrt(128)

    for (int t0 = 0; t0 < q0 + 64; t0 += 32) {
        __syncthreads();

#pragma unroll
        for (int p = 0; p < 4; p++) {
            int lin = tid + p * 256;
            int d4  = (lin & 31) * 4;
            int tt  = lin >> 5;
            const float4 kv4 = *(const float4*)(kbase + (size_t)(t0 + tt) * HD + d4);
            Ks[d4 + 0][tt] = kv4.x;
            Ks[d4 + 1][tt] = kv4.y;
            Ks[d4 + 2][tt] = kv4.z;
            Ks[d4 + 3][tt] = kv4.w;
            *(float4*)&Vs[tt][d4] = *(const float4*)(vbase + (size_t)(t0 + tt) * HD + d4);
        }
        __syncthreads();

        float s[4][2] = {};
#pragma unroll 8
        for (int kk = 0; kk < 128; kk++) {
            float a[4], bb[2];
#pragma unroll
            for (int i = 0; i < 4; i++) a[i] = Qs[kk][ty * 4 + i];
#pragma unroll
            for (int j = 0; j < 2; j++) bb[j] = Ks[kk][tx * 2 + j];
#pragma unroll
            for (int i = 0; i < 4; i++)
#pragma unroll
                for (int j = 0; j < 2; j++) s[i][j] += a[i] * bb[j];
        }

#pragma unroll
        for (int i = 0; i < 4; i++) {
            const int qg = q0 + ty * 4 + i;
#pragma unroll
            for (int j = 0; j < 2; j++) {
                const int tg = t0 + tx * 2 + j;
                s[i][j] = (tg > qg) ? -INFINITY : s[i][j] * scale;
            }
            float tmax = fmaxf(s[i][0], s[i][1]);
#pragma unroll
            for (int msk = 1; msk < 16; msk <<= 1)
                tmax = fmaxf(tmax, __shfl_xor(tmax, msk, 64));

            const float mnew  = fmaxf(m_i[i], tmax);
            const float alpha = __expf(m_i[i] - mnew);
            const float p0 = __expf(s[i][0] - mnew);
            const float p1 = __expf(s[i][1] - mnew);
            float psum = p0 + p1;
#pragma unroll
            for (int msk = 1; msk < 16; msk <<= 1)
                psum += __shfl_xor(psum, msk, 64);

            l_i[i] = l_i[i] * alpha + psum;
            m_i[i] = mnew;
#pragma unroll
            for (int c = 0; c < 8; c++) o[i][c] *= alpha;

            Ps[tx * 2 + 0][ty * 4 + i] = p0;
            Ps[tx * 2 + 1][ty * 4 + i] = p1;
        }
        __syncthreads();

#pragma unroll 4
        for (int kk = 0; kk < 32; kk++) {
            float a[4], bb[8];
#pragma unroll
            for (int i = 0; i < 4; i++) a[i] = Ps[kk][ty * 4 + i];
#pragma unroll
            for (int c = 0; c < 8; c++) bb[c] = Vs[kk][tx * 8 + c];
#pragma unroll
            for (int i = 0; i < 4; i++)
#pragma unroll
                for (int c = 0; c < 8; c++) o[i][c] += a[i] * bb[c];
        }
    }

#pragma unroll
    for (int i = 0; i < 4; i++) {
        const float inv = 1.0f / l_i[i];
        const int qg = q0 + ty * 4 + i;
        bf16* dst = ctx + (((size_t)(b * S + qg)) * NH + h) * HD + tx * 8;
#pragma unroll
        for (int c = 0; c < 8; c++) dst[c] = __float2bfloat16(o[i][c] * inv);
    }
}

// ---------------------------------------------------------------------------
extern "C" void kernel_launch(void* const* d_in, const int* in_sizes, int n_in,
                              void* d_out, int out_size, void* d_ws, size_t ws_size,
                              hipStream_t stream) {
    const float* x    = (const float*)d_in[0];
    const float* cosT = (const float*)d_in[2];
    const float* sinT = (const float*)d_in[3];
    const float* Wq   = (const float*)d_in[4];
    const float* Wk   = (const float*)d_in[5];
    const float* Wv   = (const float*)d_in[6];
    const float* Wo   = (const float*)d_in[7];
    const float* qsc  = (const float*)d_in[8];
    const float* ksc  = (const float*)d_in[9];
    float* out = (float*)d_out;

    // Workspace layout (floats):
    float* q_ws = (float*)d_ws;                          // 8,388,608 f
    float* k_ws = q_ws + (size_t)B * NH * S * HD;        // 2,097,152 f
    float* v_ws = k_ws + (size_t)B * KV * S * HD;        // 2,097,152 f
    bf16*  xb   = (bf16*)(v_ws + (size_t)B * KV * S * HD); // 8,388,608 bf16
    bf16*  wq_t = xb + (size_t)M_ROWS * D;               // 4,194,304 bf16
    bf16*  wk_t = wq_t + (size_t)D * (KV * HD);          // note: Wq^T is N*K = 2048*2048
    // careful: wq_t holds N*K = (NH*HD)*D = 4,194,304
    bf16*  wv_t = wk_t + (size_t)(KV * HD) * D;          // 1,048,576 each
    bf16*  ctx_b = xb;          // reuse: x no longer needed after projections
    bf16*  wo_t  = (bf16*)q_ws; // reuse: q no longer needed after flash_attn

    // fix wk_t offset (wq_t size is (NH*HD)*D):
    wk_t = wq_t + (size_t)(NH * HD) * D;
    wv_t = wk_t + (size_t)(KV * HD) * D;

    // 1) casts / transposes
    cast_f32_bf16<<<(M_ROWS * D / 4 + 255) / 256, 256, 0, stream>>>(x, xb, M_ROWS * D / 4);
    tcast<<<dim3((NH * HD) / 32, D / 32), 256, 0, stream>>>(Wq, wq_t, D, NH * HD);
    tcast<<<dim3((KV * HD) / 32, D / 32), 256, 0, stream>>>(Wk, wk_t, D, KV * HD);
    tcast<<<dim3((KV * HD) / 32, D / 32), 256, 0, stream>>>(Wv, wv_t, D, KV * HD);

    // 2) projections (MFMA)
    gemm_bt<true><<<dim3((NH * HD) / 128, M_ROWS / 128), 256, 0, stream>>>(xb, wq_t, q_ws, NH * HD, D, NH);
    gemm_bt<true><<<dim3((KV * HD) / 128, M_ROWS / 128), 256, 0, stream>>>(xb, wk_t, k_ws, KV * HD, D, KV);
    gemm_bt<true><<<dim3((KV * HD) / 128, M_ROWS / 128), 256, 0, stream>>>(xb, wv_t, v_ws, KV * HD, D, KV);

    // 3) RMSNorm + RoPE on q and k
    rms_rope<<<B * NH * S, 128, 0, stream>>>(q_ws, qsc, cosT, sinT);
    rms_rope<<<B * KV * S, 128, 0, stream>>>(k_ws, ksc, cosT, sinT);

    // 4) flash attention -> bf16 ctx (overwrites xb region; xb dead by now)
    flash_attn<<<dim3(S / 64, NH, B), dim3(16, 16), 0, stream>>>(q_ws, k_ws, v_ws, ctx_b);

    // 5) transpose Wo (into q region; q dead by now), then output GEMM
    tcast<<<dim3(D / 32, D / 32), 256, 0, stream>>>(Wo, wo_t, D, D);
    gemm_bt<false><<<dim3(D / 128, M_ROWS / 128), 256, 0, stream>>>(ctx_b, wo_t, out, D, D, 0);
}

// Round 6
// 676.287 us; speedup vs baseline: 15.5686x; 2.3990x over previous
//
#include <hip/hip_runtime.h>
#include <hip/hip_bf16.h>
#include <math.h>

// Problem constants: b=2, s=2048, d_in=2048, nh=16, kv=4, hd=128
#define B  2
#define S  2048
#define D  2048
#define NH 16
#define KV 4
#define HD 128
#define G  (NH / KV)   // 4
#define M_ROWS (B * S) // 4096

typedef __hip_bfloat16 bf16;
typedef __attribute__((ext_vector_type(8))) short s16x8;   // 8 bf16 (4 VGPRs)
typedef __attribute__((ext_vector_type(4))) float f32x4;   // MFMA acc

__device__ __forceinline__ short bf16_bits(float f) {
    bf16 t = __float2bfloat16(f);
    return *reinterpret_cast<short*>(&t);
}

// ---------------------------------------------------------------------------
// fp32 -> bf16 cast (4 elems/thread)
// ---------------------------------------------------------------------------
__global__ __launch_bounds__(256) void cast_f32_bf16(const float* __restrict__ in,
                                                     bf16* __restrict__ o, int n4) {
    int i = blockIdx.x * 256 + threadIdx.x;
    if (i >= n4) return;
    float4 v = ((const float4*)in)[i];
    ushort4 u;
    u.x = (unsigned short)bf16_bits(v.x);
    u.y = (unsigned short)bf16_bits(v.y);
    u.z = (unsigned short)bf16_bits(v.z);
    u.w = (unsigned short)bf16_bits(v.w);
    ((ushort4*)o)[i] = u;
}

// ---------------------------------------------------------------------------
// W (K x N fp32, row-major) -> Wt (N x K bf16, row-major), tiled transpose
// ---------------------------------------------------------------------------
__global__ __launch_bounds__(256) void tcast(const float* __restrict__ W,
                                             bf16* __restrict__ Wt, int K, int N) {
    __shared__ float T[32][33];
    const int n0 = blockIdx.x * 32, k0 = blockIdx.y * 32;
    const int tx = threadIdx.x & 31, ty = threadIdx.x >> 5; // ty 0..7
#pragma unroll
    for (int i = 0; i < 4; i++)
        T[ty + i * 8][tx] = W[(size_t)(k0 + ty + i * 8) * N + n0 + tx];
    __syncthreads();
#pragma unroll
    for (int i = 0; i < 4; i++)
        Wt[(size_t)(n0 + ty + i * 8) * K + k0 + tx] = __float2bfloat16(T[tx][ty + i * 8]);
}

// ---------------------------------------------------------------------------
// MFMA GEMM: A (M x K bf16) @ Bt (N x K bf16) -> out.
// Block tile 128x128, BK=32, 4 waves (64x64 quadrant, 4x4 of 16x16x32 MFMA).
// MODE 0: fp32 out[m*N+n]
// MODE 1: fp32 head-major out[((b*H+h)*S+si)*HD + d]
// MODE 2: bf16 V^T      out[((b*H+h)*HD+d)*S  + si]
// ---------------------------------------------------------------------------
template<int MODE>
__global__ __launch_bounds__(256) void gemm_bt(const bf16* __restrict__ A,
                                               const bf16* __restrict__ Bt,
                                               void* __restrict__ outv,
                                               int N, int K, int H) {
    const int m0 = blockIdx.y * 128;
    const int n0 = blockIdx.x * 128;
    const int tid  = threadIdx.x;
    const int wave = tid >> 6;
    const int lane = tid & 63;
    const int mw = (wave >> 1) * 64;
    const int nw = (wave & 1) * 64;

    __shared__ short Al[128 * 40];
    __shared__ short Bl[128 * 40];

    f32x4 acc[4][4] = {};

    const int fr = lane & 15;
    const int fq = (lane >> 4) * 8;

    for (int k0 = 0; k0 < K; k0 += 32) {
        __syncthreads();
#pragma unroll
        for (int cc = 0; cc < 2; cc++) {
            int c = tid + cc * 256;
            int row = c >> 2, part = (c & 3) * 8;
            *(uint4*)(&Al[row * 40 + part]) =
                *(const uint4*)(A + (size_t)(m0 + row) * K + k0 + part);
            *(uint4*)(&Bl[row * 40 + part]) =
                *(const uint4*)(Bt + (size_t)(n0 + row) * K + k0 + part);
        }
        __syncthreads();

        s16x8 af[4], bfr[4];
#pragma unroll
        for (int i = 0; i < 4; i++) {
            af[i]  = *(const s16x8*)(&Al[(mw + i * 16 + fr) * 40 + fq]);
            bfr[i] = *(const s16x8*)(&Bl[(nw + i * 16 + fr) * 40 + fq]);
        }
#pragma unroll
        for (int i = 0; i < 4; i++)
#pragma unroll
            for (int j = 0; j < 4; j++)
                acc[i][j] = __builtin_amdgcn_mfma_f32_16x16x32_bf16(af[i], bfr[j], acc[i][j], 0, 0, 0);
    }

    const int col_l = lane & 15;
    const int row_l = (lane >> 4) * 4;
#pragma unroll
    for (int i = 0; i < 4; i++)
#pragma unroll
        for (int j = 0; j < 4; j++) {
            int m_base = m0 + mw + i * 16 + row_l;   // 4 consecutive m
            int n = n0 + nw + j * 16 + col_l;
            if (MODE == 2) {
                int bb = m_base >> 11, si = m_base & (S - 1);
                int hh = n >> 7, d = n & (HD - 1);
                ushort4 u;
                u.x = (unsigned short)bf16_bits(acc[i][j][0]);
                u.y = (unsigned short)bf16_bits(acc[i][j][1]);
                u.z = (unsigned short)bf16_bits(acc[i][j][2]);
                u.w = (unsigned short)bf16_bits(acc[i][j][3]);
                *(ushort4*)((bf16*)outv + (((size_t)(bb * H + hh)) * HD + d) * S + si) = u;
            } else {
#pragma unroll
                for (int r = 0; r < 4; r++) {
                    int m = m_base + r;
                    if (MODE == 1) {
                        int bb = m >> 11, si = m & (S - 1);
                        int h = n >> 7, d = n & (HD - 1);
                        ((float*)outv)[(((size_t)(bb * H + h)) * S + si) * HD + d] = acc[i][j][r];
                    } else {
                        ((float*)outv)[(size_t)m * N + n] = acc[i][j][r];
                    }
                }
            }
        }
}

// ---------------------------------------------------------------------------
// RMSNorm (over hd=128) + RoPE; fp32 head-major in -> bf16 same layout out.
// SC: fold 1/sqrt(hd) into output (for Q).
// ---------------------------------------------------------------------------
template<bool SC>
__global__ __launch_bounds__(128) void rms_rope_o(const float* __restrict__ in,
                                                  bf16* __restrict__ out,
                                                  const float* __restrict__ scale,
                                                  const float* __restrict__ cosT,
                                                  const float* __restrict__ sinT) {
    const int r = blockIdx.x;
    const int d = threadIdx.x;
    const int si = r & (S - 1);
    const float* row = in + (size_t)r * HD;

    float val = row[d];

    __shared__ float red[HD];
    __shared__ float nrm[HD];
    red[d] = val * val;
    __syncthreads();
#pragma unroll
    for (int off = 64; off > 0; off >>= 1) {
        if (d < off) red[d] += red[d + off];
        __syncthreads();
    }
    const float ms = red[0] * (1.0f / HD);
    const float rinv = rsqrtf(ms + 1e-6f);

    const float nv = val * rinv * scale[d];
    nrm[d] = nv;
    __syncthreads();

    const int pd = (d < 64) ? (d + 64) : (d - 64);
    const float part = nrm[pd];
    const float rot = (d < 64) ? -part : part;

    const float c = cosT[(size_t)si * HD + d];
    const float s = sinT[(size_t)si * HD + d];

    float res = nv * c + rot * s;
    if (SC) res *= 0.08838834764831845f; // 1/sqrt(128)
    out[(size_t)r * HD + d] = __float2bfloat16(res);
}

// ---------------------------------------------------------------------------
// MFMA flash attention. 256 threads = 4 waves; Q-tile 64 (16 rows/wave);
// KV-tile 64. qb: (b,NH,S,HD) bf16 (pre-scaled); kb: (b,KV,S,HD) bf16;
// vtb: (b,KV,HD,S) bf16 (V transposed). ctx out: (b,s,nh,hd) bf16.
// ---------------------------------------------------------------------------
__global__ __launch_bounds__(256) void flash_mfma(const bf16* __restrict__ qb,
                                                  const bf16* __restrict__ kb,
                                                  const bf16* __restrict__ vtb,
                                                  bf16* __restrict__ ctx) {
    const int q0 = blockIdx.x * 64;
    const int h  = blockIdx.y;
    const int b  = blockIdx.z;
    const int kvh = h / G;
    const int tid  = threadIdx.x;
    const int wave = tid >> 6;
    const int lane = tid & 63;
    const int quad = lane >> 4;
    const int l16  = lane & 15;
    const int quad8 = quad * 8;

    __shared__ short Ks[64][136];    // [t][d]  17.4 KB
    __shared__ short Vs[128][72];    // [d][t]  18.4 KB
    __shared__ short Ps[4][16][72];  // per-wave [q][t]  9.2 KB

    const bf16* qbase = qb  + ((size_t)(b * NH + h))  * S * HD;
    const bf16* kbase = kb  + ((size_t)(b * KV + kvh)) * S * HD;
    const bf16* vbase = vtb + ((size_t)(b * KV + kvh)) * HD * S;

    // Q A-fragments: row m = l16 (wave rows q0+wave*16+l16), k = ks*32+quad*8
    s16x8 qf[4];
    {
        const bf16* qrow = qbase + (size_t)(q0 + wave * 16 + l16) * HD + quad8;
#pragma unroll
        for (int ks = 0; ks < 4; ks++)
            qf[ks] = *(const s16x8*)(qrow + ks * 32);
    }

    f32x4 o[8] = {};
    float m_i[4], l_i[4];
#pragma unroll
    for (int r = 0; r < 4; r++) { m_i[r] = -INFINITY; l_i[r] = 0.0f; }

    for (int t0 = 0; t0 <= q0; t0 += 64) {
        __syncthreads(); // all waves done with Ks/Vs of prev iteration

        // stage K tile: 64 t-rows x 128 d = 1024 16B chunks
#pragma unroll
        for (int it = 0; it < 4; it++) {
            int c = tid + it * 256;          // 0..1023
            int row = c >> 4, part = (c & 15) * 8;
            *(uint4*)&Ks[row][part] =
                *(const uint4*)(kbase + (size_t)(t0 + row) * HD + part);
        }
        // stage V^T tile: 128 d-rows x 64 t = 1024 16B chunks
#pragma unroll
        for (int it = 0; it < 4; it++) {
            int c = tid + it * 256;          // 0..1023
            int row = c >> 3, part = (c & 7) * 8;
            *(uint4*)&Vs[row][part] =
                *(const uint4*)(vbase + (size_t)row * S + t0 + part);
        }
        __syncthreads();

        // ---- S = Q K^T : per wave 16q x 64t ----
        f32x4 sa[4] = {};
#pragma unroll
        for (int ks = 0; ks < 4; ks++) {
#pragma unroll
            for (int n = 0; n < 4; n++) {
                s16x8 kf = *(const s16x8*)&Ks[n * 16 + l16][ks * 32 + quad8];
                sa[n] = __builtin_amdgcn_mfma_f32_16x16x32_bf16(qf[ks], kf, sa[n], 0, 0, 0);
            }
        }

        // ---- online softmax; lane rows = quad*4 + r ----
        const bool diag = (t0 == q0);
#pragma unroll
        for (int r = 0; r < 4; r++) {
            const int qg = q0 + wave * 16 + quad * 4 + r;
            float sv[4];
#pragma unroll
            for (int n = 0; n < 4; n++) {
                float v = sa[n][r];
                if (diag && (t0 + n * 16 + l16 > qg)) v = -INFINITY;
                sv[n] = v;
            }
            float rm = fmaxf(fmaxf(sv[0], sv[1]), fmaxf(sv[2], sv[3]));
#pragma unroll
            for (int msk = 1; msk < 16; msk <<= 1)
                rm = fmaxf(rm, __shfl_xor(rm, msk, 64));

            const float mnew  = fmaxf(m_i[r], rm);
            const float alpha = __expf(m_i[r] - mnew);
            float ps = 0.0f;
#pragma unroll
            for (int n = 0; n < 4; n++) {
                float p = __expf(sv[n] - mnew);
                ps += p;
                Ps[wave][quad * 4 + r][n * 16 + l16] = bf16_bits(p);
            }
#pragma unroll
            for (int msk = 1; msk < 16; msk <<= 1)
                ps += __shfl_xor(ps, msk, 64);

            l_i[r] = l_i[r] * alpha + ps;
            m_i[r] = mnew;
#pragma unroll
            for (int n = 0; n < 8; n++) o[n][r] *= alpha;
        }

        // ---- PV: O(16q x 128d) += P(16x64) V(64x128), per wave ----
#pragma unroll
        for (int ks = 0; ks < 2; ks++) {
            s16x8 pf = *(const s16x8*)&Ps[wave][l16][ks * 32 + quad8];
#pragma unroll
            for (int n = 0; n < 8; n++) {
                s16x8 vf = *(const s16x8*)&Vs[n * 16 + l16][ks * 32 + quad8];
                o[n] = __builtin_amdgcn_mfma_f32_16x16x32_bf16(pf, vf, o[n], 0, 0, 0);
            }
        }
    }

    // ---- epilogue ----
#pragma unroll
    for (int r = 0; r < 4; r++) {
        const float inv = 1.0f / l_i[r];
        const int qg = q0 + wave * 16 + quad * 4 + r;
        bf16* dst = ctx + (((size_t)(b * S + qg)) * NH + h) * HD;
#pragma unroll
        for (int n = 0; n < 8; n++)
            dst[n * 16 + l16] = __float2bfloat16(o[n][r] * inv);
    }
}

// ---------------------------------------------------------------------------
extern "C" void kernel_launch(void* const* d_in, const int* in_sizes, int n_in,
                              void* d_out, int out_size, void* d_ws, size_t ws_size,
                              hipStream_t stream) {
    const float* x    = (const float*)d_in[0];
    const float* cosT = (const float*)d_in[2];
    const float* sinT = (const float*)d_in[3];
    const float* Wq   = (const float*)d_in[4];
    const float* Wk   = (const float*)d_in[5];
    const float* Wv   = (const float*)d_in[6];
    const float* Wo   = (const float*)d_in[7];
    const float* qsc  = (const float*)d_in[8];
    const float* ksc  = (const float*)d_in[9];
    float* out = (float*)d_out;

    // Workspace packing (72 MB total), byte offsets:
    char* w = (char*)d_ws;
    float* q_ws = (float*)(w);                  // [0,32M)  fp32 q head-major
    bf16*  wo_t = (bf16*)(w);                   // [0,8M)   after q dead
    bf16*  ctx_b= (bf16*)(w + (8u << 20));      // [8M,24M) after q dead
    float* k_ws = (float*)(w + (32u << 20));    // [32M,40M) fp32 k head-major
    bf16*  xb   = (bf16*)(w + (40u << 20));     // [40M,56M)
    bf16*  qb   = (bf16*)(w + (40u << 20));     // same region, after projections
    bf16*  wq_t = (bf16*)(w + (56u << 20));     // [56M,64M)
    bf16*  kb   = (bf16*)(w + (56u << 20));     // same region, after projections
    bf16*  wk_t = (bf16*)(w + (64u << 20));     // [64M,66M)
    bf16*  wv_t = (bf16*)(w + (66u << 20));     // [66M,68M)
    bf16*  vtb  = (bf16*)(w + (68u << 20));     // [68M,72M)

    // 1) casts / transposes
    cast_f32_bf16<<<(M_ROWS * D / 4 + 255) / 256, 256, 0, stream>>>(x, xb, M_ROWS * D / 4);
    tcast<<<dim3((NH * HD) / 32, D / 32), 256, 0, stream>>>(Wq, wq_t, D, NH * HD);
    tcast<<<dim3((KV * HD) / 32, D / 32), 256, 0, stream>>>(Wk, wk_t, D, KV * HD);
    tcast<<<dim3((KV * HD) / 32, D / 32), 256, 0, stream>>>(Wv, wv_t, D, KV * HD);

    // 2) projections (MFMA): q,k -> fp32 head-major; v -> bf16 V^T
    gemm_bt<1><<<dim3((NH * HD) / 128, M_ROWS / 128), 256, 0, stream>>>(xb, wq_t, q_ws, NH * HD, D, NH);
    gemm_bt<1><<<dim3((KV * HD) / 128, M_ROWS / 128), 256, 0, stream>>>(xb, wk_t, k_ws, KV * HD, D, KV);
    gemm_bt<2><<<dim3((KV * HD) / 128, M_ROWS / 128), 256, 0, stream>>>(xb, wv_t, vtb, KV * HD, D, KV);

    // 3) RMSNorm + RoPE -> bf16 (q pre-scaled by 1/sqrt(hd))
    rms_rope_o<true ><<<B * NH * S, 128, 0, stream>>>(q_ws, qb, qsc, cosT, sinT);
    rms_rope_o<false><<<B * KV * S, 128, 0, stream>>>(k_ws, kb, ksc, cosT, sinT);

    // 4) Wo^T into dead q region
    tcast<<<dim3(D / 32, D / 32), 256, 0, stream>>>(Wo, wo_t, D, D);

    // 5) MFMA flash attention -> bf16 ctx
    flash_mfma<<<dim3(S / 64, NH, B), 256, 0, stream>>>(qb, kb, vtb, ctx_b);

    // 6) output projection
    gemm_bt<0><<<dim3(D / 128, M_ROWS / 128), 256, 0, stream>>>(ctx_b, wo_t, out, D, D, 0);
}

// Round 10
// 540.999 us; speedup vs baseline: 19.4619x; 1.2501x over previous
//
#include <hip/hip_runtime.h>
#include <hip/hip_bf16.h>
#include <math.h>

// Problem constants: b=2, s=2048, d_in=2048, nh=16, kv=4, hd=128
#define B  2
#define S  2048
#define D  2048
#define NH 16
#define KV 4
#define HD 128
#define G  (NH / KV)   // 4
#define M_ROWS (B * S) // 4096

typedef __hip_bfloat16 bf16;
typedef __attribute__((ext_vector_type(8))) short s16x8;   // 8 bf16 (4 VGPRs)
typedef __attribute__((ext_vector_type(4))) float f32x4;   // MFMA acc

__device__ __forceinline__ short bf16_bits(float f) {
    bf16 t = __float2bfloat16(f);
    return *reinterpret_cast<short*>(&t);
}

// ---------------------------------------------------------------------------
// fp32 -> bf16 cast (4 elems/thread)
// ---------------------------------------------------------------------------
__global__ __launch_bounds__(256) void cast_f32_bf16(const float* __restrict__ in,
                                                     bf16* __restrict__ o, int n4) {
    int i = blockIdx.x * 256 + threadIdx.x;
    if (i >= n4) return;
    float4 v = ((const float4*)in)[i];
    ushort4 u;
    u.x = (unsigned short)bf16_bits(v.x);
    u.y = (unsigned short)bf16_bits(v.y);
    u.z = (unsigned short)bf16_bits(v.z);
    u.w = (unsigned short)bf16_bits(v.w);
    ((ushort4*)o)[i] = u;
}

// ---------------------------------------------------------------------------
// W (K x N fp32, row-major) -> Wt (N x K bf16, row-major), tiled transpose
// ---------------------------------------------------------------------------
__global__ __launch_bounds__(256) void tcast(const float* __restrict__ W,
                                             bf16* __restrict__ Wt, int K, int N) {
    __shared__ float T[32][33];
    const int n0 = blockIdx.x * 32, k0 = blockIdx.y * 32;
    const int tx = threadIdx.x & 31, ty = threadIdx.x >> 5; // ty 0..7
#pragma unroll
    for (int i = 0; i < 4; i++)
        T[ty + i * 8][tx] = W[(size_t)(k0 + ty + i * 8) * N + n0 + tx];
    __syncthreads();
#pragma unroll
    for (int i = 0; i < 4; i++)
        Wt[(size_t)(n0 + ty + i * 8) * K + k0 + tx] = __float2bfloat16(T[tx][ty + i * 8]);
}

// ---------------------------------------------------------------------------
// MFMA GEMM: A (M x K bf16) @ Bt (N x K bf16) -> out.
// Block tile 128x128, BK=32, 4 waves (64x64 quadrant, 4x4 of 16x16x32 MFMA).
// MODE 0: fp32 out[m*N+n]
// MODE 1: fp32 head-major out[((b*H+h)*S+si)*HD + d]
// MODE 2: bf16 V^T      out[((b*H+h)*HD+d)*S  + si]
// ---------------------------------------------------------------------------
template<int MODE>
__global__ __launch_bounds__(256) void gemm_bt(const bf16* __restrict__ A,
                                               const bf16* __restrict__ Bt,
                                               void* __restrict__ outv,
                                               int N, int K, int H) {
    const int m0 = blockIdx.y * 128;
    const int n0 = blockIdx.x * 128;
    const int tid  = threadIdx.x;
    const int wave = tid >> 6;
    const int lane = tid & 63;
    const int mw = (wave >> 1) * 64;
    const int nw = (wave & 1) * 64;

    __shared__ short Al[128 * 40];
    __shared__ short Bl[128 * 40];

    f32x4 acc[4][4] = {};

    const int fr = lane & 15;
    const int fq = (lane >> 4) * 8;

    for (int k0 = 0; k0 < K; k0 += 32) {
        __syncthreads();
#pragma unroll
        for (int cc = 0; cc < 2; cc++) {
            int c = tid + cc * 256;
            int row = c >> 2, part = (c & 3) * 8;
            *(uint4*)(&Al[row * 40 + part]) =
                *(const uint4*)(A + (size_t)(m0 + row) * K + k0 + part);
            *(uint4*)(&Bl[row * 40 + part]) =
                *(const uint4*)(Bt + (size_t)(n0 + row) * K + k0 + part);
        }
        __syncthreads();

        s16x8 af[4], bfr[4];
#pragma unroll
        for (int i = 0; i < 4; i++) {
            af[i]  = *(const s16x8*)(&Al[(mw + i * 16 + fr) * 40 + fq]);
            bfr[i] = *(const s16x8*)(&Bl[(nw + i * 16 + fr) * 40 + fq]);
        }
#pragma unroll
        for (int i = 0; i < 4; i++)
#pragma unroll
            for (int j = 0; j < 4; j++)
                acc[i][j] = __builtin_amdgcn_mfma_f32_16x16x32_bf16(af[i], bfr[j], acc[i][j], 0, 0, 0);
    }

    const int col_l = lane & 15;
    const int row_l = (lane >> 4) * 4;
#pragma unroll
    for (int i = 0; i < 4; i++)
#pragma unroll
        for (int j = 0; j < 4; j++) {
            int m_base = m0 + mw + i * 16 + row_l;   // 4 consecutive m
            int n = n0 + nw + j * 16 + col_l;
            if (MODE == 2) {
                int bb = m_base >> 11, si = m_base & (S - 1);
                int hh = n >> 7, d = n & (HD - 1);
                ushort4 u;
                u.x = (unsigned short)bf16_bits(acc[i][j][0]);
                u.y = (unsigned short)bf16_bits(acc[i][j][1]);
                u.z = (unsigned short)bf16_bits(acc[i][j][2]);
                u.w = (unsigned short)bf16_bits(acc[i][j][3]);
                *(ushort4*)((bf16*)outv + (((size_t)(bb * H + hh)) * HD + d) * S + si) = u;
            } else {
#pragma unroll
                for (int r = 0; r < 4; r++) {
                    int m = m_base + r;
                    if (MODE == 1) {
                        int bb = m >> 11, si = m & (S - 1);
                        int h = n >> 7, d = n & (HD - 1);
                        ((float*)outv)[(((size_t)(bb * H + h)) * S + si) * HD + d] = acc[i][j][r];
                    } else {
                        ((float*)outv)[(size_t)m * N + n] = acc[i][j][r];
                    }
                }
            }
        }
}

// ---------------------------------------------------------------------------
// RMSNorm (over hd=128) + RoPE; fp32 head-major in -> bf16 same layout out.
// SC: fold 1/sqrt(hd) into output (for Q).
// ---------------------------------------------------------------------------
template<bool SC>
__global__ __launch_bounds__(128) void rms_rope_o(const float* __restrict__ in,
                                                  bf16* __restrict__ out,
                                                  const float* __restrict__ scale,
                                                  const float* __restrict__ cosT,
                                                  const float* __restrict__ sinT) {
    const int r = blockIdx.x;
    const int d = threadIdx.x;
    const int si = r & (S - 1);
    const float* row = in + (size_t)r * HD;

    float val = row[d];

    __shared__ float red[HD];
    __shared__ float nrm[HD];
    red[d] = val * val;
    __syncthreads();
#pragma unroll
    for (int off = 64; off > 0; off >>= 1) {
        if (d < off) red[d] += red[d + off];
        __syncthreads();
    }
    const float ms = red[0] * (1.0f / HD);
    const float rinv = rsqrtf(ms + 1e-6f);

    const float nv = val * rinv * scale[d];
    nrm[d] = nv;
    __syncthreads();

    const int pd = (d < 64) ? (d + 64) : (d - 64);
    const float part = nrm[pd];
    const float rot = (d < 64) ? -part : part;

    const float c = cosT[(size_t)si * HD + d];
    const float s = sinT[(size_t)si * HD + d];

    float res = nv * c + rot * s;
    if (SC) res *= 0.08838834764831845f; // 1/sqrt(128)
    out[(size_t)r * HD + d] = __float2bfloat16(res);
}

// ---------------------------------------------------------------------------
// MFMA flash attention v3: head-merged, causally-paired, fixed-max softmax,
// single-buffered K/V staging with register prefetch (54 KB LDS).
// Block = (pair p, kvh, b); 4 waves = the 4 q-heads sharing this KV group.
// Each wave handles 32 q rows per phase; phases = q-tiles {p, 63-p}.
// qb: (b,NH,S,HD) bf16 pre-scaled by 1/sqrt(hd); kb: (b,KV,S,HD) bf16;
// vtb: (b,KV,HD,S) bf16. ctx: (b,s,nh,hd) bf16.
// Scores bounded: ||q||=||k||=sqrt(128) => |s| <= 11.32; use fixed max 13.
// ---------------------------------------------------------------------------
__global__ __launch_bounds__(256) void flash_mfma3(const bf16* __restrict__ qb,
                                                   const bf16* __restrict__ kb,
                                                   const bf16* __restrict__ vtb,
                                                   bf16* __restrict__ ctx) {
    const int p    = blockIdx.x;         // pair index 0..31
    const int kvh  = blockIdx.y;
    const int b    = blockIdx.z;
    const int tid  = threadIdx.x;
    const int wave = tid >> 6;
    const int lane = tid & 63;
    const int quad = lane >> 4;
    const int l16  = lane & 15;
    const int quad8 = quad * 8;
    const int h = kvh * G + wave;        // this wave's q-head

    __shared__ short Ks[64][136];        // [t][d]  17.4 KB
    __shared__ short Vs[128][72];        // [d][t]  18.4 KB
    __shared__ short Ps[4][32][72];      // per-wave [q][t] 18.4 KB

    const bf16* qbase = qb  + ((size_t)(b * NH + h))   * S * HD;
    const bf16* kbase = kb  + ((size_t)(b * KV + kvh)) * S * HD;
    const bf16* vbase = vtb + ((size_t)(b * KV + kvh)) * HD * S;

    const int nA   = (p >> 1) + 1;       // KV tiles for q-tile p
    const int pB   = 63 - p;
    const int nB   = (pB >> 1) + 1;      // KV tiles for q-tile 63-p
    const int nTot = nA + nB;            // always 33

    int q0 = 32 * p;

    // Q A-fragments for phase A: rows q0 + s*16 + l16, k = ks*32 + quad8
    s16x8 qf[2][4];
#pragma unroll
    for (int s = 0; s < 2; s++) {
        const bf16* qrow = qbase + (size_t)(q0 + s * 16 + l16) * HD + quad8;
#pragma unroll
        for (int ks = 0; ks < 4; ks++)
            qf[s][ks] = *(const s16x8*)(qrow + ks * 32);
    }

    f32x4 o[2][8] = {};
    float l[2][4] = {};

    // prologue: prefetch tile 0 into regs
    uint4 kreg[4], vreg[4];
#pragma unroll
    for (int it = 0; it < 4; it++) {
        int c = tid + it * 256;
        kreg[it] = *(const uint4*)(kbase + (size_t)(c >> 4) * HD + (c & 15) * 8);
        vreg[it] = *(const uint4*)(vbase + (size_t)(c >> 3) * S + (c & 7) * 8);
    }

    for (int i = 0; i < nTot; i++) {
        // commit prefetched tile to LDS
#pragma unroll
        for (int it = 0; it < 4; it++) {
            int c = tid + it * 256;
            *(uint4*)&Ks[c >> 4][(c & 15) * 8] = kreg[it];
            *(uint4*)&Vs[c >> 3][(c & 7) * 8] = vreg[it];
        }
        __syncthreads();   // LDS tile ready for all waves

        const int t0 = (i < nA) ? 64 * i : 64 * (i - nA);

        // issue next tile's global loads (in flight during compute)
        if (i + 1 < nTot) {
            const int tn = (i + 1 < nA) ? 64 * (i + 1) : 64 * (i + 1 - nA);
#pragma unroll
            for (int it = 0; it < 4; it++) {
                int c = tid + it * 256;
                kreg[it] = *(const uint4*)(kbase + (size_t)(tn + (c >> 4)) * HD + (c & 15) * 8);
                vreg[it] = *(const uint4*)(vbase + (size_t)(c >> 3) * S + tn + (c & 7) * 8);
            }
        }

        // ---- S = Q K^T : 32q x 64t per wave ----
        f32x4 sa[2][4] = {};
#pragma unroll
        for (int ks = 0; ks < 4; ks++) {
#pragma unroll
            for (int n = 0; n < 4; n++) {
                s16x8 kf = *(const s16x8*)&Ks[n * 16 + l16][ks * 32 + quad8];
#pragma unroll
                for (int s = 0; s < 2; s++)
                    sa[s][n] = __builtin_amdgcn_mfma_f32_16x16x32_bf16(qf[s][ks], kf, sa[s][n], 0, 0, 0);
            }
        }

        // ---- fixed-max exp: p = exp(s - 13); no reductions, no rescale ----
        const bool msk = (t0 + 63 > q0);  // only possibly true on a phase's last tile
#pragma unroll
        for (int s = 0; s < 2; s++)
#pragma unroll
            for (int r = 0; r < 4; r++) {
                const int qg = q0 + s * 16 + quad * 4 + r;
#pragma unroll
                for (int n = 0; n < 4; n++) {
                    float v = sa[s][n][r];
                    if (msk && (t0 + n * 16 + l16 > qg)) v = -INFINITY;
                    float pv = __expf(v - 13.0f);
                    l[s][r] += pv;
                    Ps[wave][s * 16 + quad * 4 + r][n * 16 + l16] = bf16_bits(pv);
                }
            }
        // Ps is per-wave: same-wave LDS write->read needs no barrier (proven R6).

        // ---- PV: O(32q x 128d) += P(32x64) V(64x128) ----
#pragma unroll
        for (int ks = 0; ks < 2; ks++) {
            s16x8 vf[8];
#pragma unroll
            for (int n = 0; n < 8; n++)
                vf[n] = *(const s16x8*)&Vs[n * 16 + l16][ks * 32 + quad8];
#pragma unroll
            for (int s = 0; s < 2; s++) {
                s16x8 pf = *(const s16x8*)&Ps[wave][s * 16 + l16][ks * 32 + quad8];
#pragma unroll
                for (int n = 0; n < 8; n++)
                    o[s][n] = __builtin_amdgcn_mfma_f32_16x16x32_bf16(pf, vf[n], o[s][n], 0, 0, 0);
            }
        }

        // ---- phase boundary: flush phase A, switch to q-tile 63-p ----
        if (i == nA - 1) {
#pragma unroll
            for (int s = 0; s < 2; s++)
#pragma unroll
                for (int r = 0; r < 4; r++) {
                    float ls = l[s][r];
#pragma unroll
                    for (int m = 1; m < 16; m <<= 1) ls += __shfl_xor(ls, m, 64);
                    const float inv = 1.0f / ls;
                    const int qg = q0 + s * 16 + quad * 4 + r;
                    bf16* dst = ctx + (((size_t)(b * S + qg)) * NH + h) * HD;
#pragma unroll
                    for (int n = 0; n < 8; n++)
                        dst[n * 16 + l16] = __float2bfloat16(o[s][n][r] * inv);
                }
            q0 = 32 * pB;
#pragma unroll
            for (int s = 0; s < 2; s++) {
                const bf16* qrow = qbase + (size_t)(q0 + s * 16 + l16) * HD + quad8;
#pragma unroll
                for (int ks = 0; ks < 4; ks++)
                    qf[s][ks] = *(const s16x8*)(qrow + ks * 32);
            }
#pragma unroll
            for (int s = 0; s < 2; s++) {
#pragma unroll
                for (int n = 0; n < 8; n++) o[s][n] = (f32x4){0.f, 0.f, 0.f, 0.f};
#pragma unroll
                for (int r = 0; r < 4; r++) l[s][r] = 0.0f;
            }
        }

        __syncthreads();   // all waves done reading Ks/Vs before next commit
    }

    // ---- epilogue phase B ----
#pragma unroll
    for (int s = 0; s < 2; s++)
#pragma unroll
        for (int r = 0; r < 4; r++) {
            float ls = l[s][r];
#pragma unroll
            for (int m = 1; m < 16; m <<= 1) ls += __shfl_xor(ls, m, 64);
            const float inv = 1.0f / ls;
            const int qg = q0 + s * 16 + quad * 4 + r;
            bf16* dst = ctx + (((size_t)(b * S + qg)) * NH + h) * HD;
#pragma unroll
            for (int n = 0; n < 8; n++)
                dst[n * 16 + l16] = __float2bfloat16(o[s][n][r] * inv);
        }
}

// ---------------------------------------------------------------------------
extern "C" void kernel_launch(void* const* d_in, const int* in_sizes, int n_in,
                              void* d_out, int out_size, void* d_ws, size_t ws_size,
                              hipStream_t stream) {
    const float* x    = (const float*)d_in[0];
    const float* cosT = (const float*)d_in[2];
    const float* sinT = (const float*)d_in[3];
    const float* Wq   = (const float*)d_in[4];
    const float* Wk   = (const float*)d_in[5];
    const float* Wv   = (const float*)d_in[6];
    const float* Wo   = (const float*)d_in[7];
    const float* qsc  = (const float*)d_in[8];
    const float* ksc  = (const float*)d_in[9];
    float* out = (float*)d_out;

    // Workspace packing (72 MB total), byte offsets:
    char* w = (char*)d_ws;
    float* q_ws = (float*)(w);                  // [0,32M)  fp32 q head-major
    bf16*  wo_t = (bf16*)(w);                   // [0,8M)   after q dead
    bf16*  ctx_b= (bf16*)(w + (8u << 20));      // [8M,24M) after q dead
    float* k_ws = (float*)(w + (32u << 20));    // [32M,40M) fp32 k head-major
    bf16*  xb   = (bf16*)(w + (40u << 20));     // [40M,56M)
    bf16*  qb   = (bf16*)(w + (40u << 20));     // same region, after projections
    bf16*  wq_t = (bf16*)(w + (56u << 20));     // [56M,64M)
    bf16*  kb   = (bf16*)(w + (56u << 20));     // same region, after projections
    bf16*  wk_t = (bf16*)(w + (64u << 20));     // [64M,66M)
    bf16*  wv_t = (bf16*)(w + (66u << 20));     // [66M,68M)
    bf16*  vtb  = (bf16*)(w + (68u << 20));     // [68M,72M)

    // 1) casts / transposes
    cast_f32_bf16<<<(M_ROWS * D / 4 + 255) / 256, 256, 0, stream>>>(x, xb, M_ROWS * D / 4);
    tcast<<<dim3((NH * HD) / 32, D / 32), 256, 0, stream>>>(Wq, wq_t, D, NH * HD);
    tcast<<<dim3((KV * HD) / 32, D / 32), 256, 0, stream>>>(Wk, wk_t, D, KV * HD);
    tcast<<<dim3((KV * HD) / 32, D / 32), 256, 0, stream>>>(Wv, wv_t, D, KV * HD);

    // 2) projections (MFMA): q,k -> fp32 head-major; v -> bf16 V^T
    gemm_bt<1><<<dim3((NH * HD) / 128, M_ROWS / 128), 256, 0, stream>>>(xb, wq_t, q_ws, NH * HD, D, NH);
    gemm_bt<1><<<dim3((KV * HD) / 128, M_ROWS / 128), 256, 0, stream>>>(xb, wk_t, k_ws, KV * HD, D, KV);
    gemm_bt<2><<<dim3((KV * HD) / 128, M_ROWS / 128), 256, 0, stream>>>(xb, wv_t, vtb, KV * HD, D, KV);

    // 3) RMSNorm + RoPE -> bf16 (q pre-scaled by 1/sqrt(hd))
    rms_rope_o<true ><<<B * NH * S, 128, 0, stream>>>(q_ws, qb, qsc, cosT, sinT);
    rms_rope_o<false><<<B * KV * S, 128, 0, stream>>>(k_ws, kb, ksc, cosT, sinT);

    // 4) Wo^T into dead q region
    tcast<<<dim3(D / 32, D / 32), 256, 0, stream>>>(Wo, wo_t, D, D);

    // 5) MFMA flash attention v3 -> bf16 ctx
    flash_mfma3<<<dim3(32, KV, B), 256, 0, stream>>>(qb, kb, vtb, ctx_b);

    // 6) output projection
    gemm_bt<0><<<dim3(D / 128, M_ROWS / 128), 256, 0, stream>>>(ctx_b, wo_t, out, D, D, 0);
}